// Round 5
// baseline (149.896 us; speedup 1.0000x reference)
//
#include <hip/hip_runtime.h>

// PartitionPadding: out[m][p][:] = feat[starts[m]+p][:] if p < count[m] else 0.
// B=2048, MAX_ATOMS=640, D=64. Pure data movement: 256MB read + 335.5MB write.
//
// Single fused kernel, R1 geometry (transient blocks, tight dispatch window):
//  - grid (10, 2048): block (x, m) covers one contiguous 16KB window of
//    molecule m's 160KB output slab.
//  - per block: two blockIdx-uniform binary searches on ind (scalarized by
//    compiler, L2-cached, latency-hidden across blocks) -> s, e.
//  - 4 f4 loads issued as a burst, then 4 f4 stores (direction batching).

#define BATCH 2048
#define MAXA  640
#define DF    64
#define ROWF4 16            // float4 per row (64 floats)

typedef float f4 __attribute__((ext_vector_type(4)));

__global__ __launch_bounds__(256) void pp_fused_kernel(
        const f4* __restrict__ feat,
        const int* __restrict__ ind,
        f4* __restrict__ out,
        int N) {
    const int m = blockIdx.y;

    // s = lower_bound(ind, m) — uniform across block, compiler scalarizes
    int lo = 0, hi = N;
    while (lo < hi) {
        int mid = (lo + hi) >> 1;
        if (ind[mid] < m) lo = mid + 1; else hi = mid;
    }
    const int s = lo;
    // e = lower_bound(ind, m+1), starting from s
    hi = N;
    while (lo < hi) {
        int mid = (lo + hi) >> 1;
        if (ind[mid] < m + 1) lo = mid + 1; else hi = mid;
    }
    const int e = lo;

    // block's f4 range within the molecule slab: [x*1024, x*1024+1024)
    const unsigned base = blockIdx.x * 1024u + threadIdx.x;

    // burst loads (4 independent, same direction)
    f4 v0 = (f4){0.f,0.f,0.f,0.f}, v1 = v0, v2 = v0, v3 = v0;
    {
        const unsigned r0 = base, r1 = base + 256u, r2 = base + 512u, r3 = base + 768u;
        // row p = r>>4 ; in-range iff s + p < e ; feat element = s*16 + r
        const unsigned fb = (unsigned)s * ROWF4;
        if (s + (int)(r0 >> 4) < e) v0 = feat[fb + r0];
        if (s + (int)(r1 >> 4) < e) v1 = feat[fb + r1];
        if (s + (int)(r2 >> 4) < e) v2 = feat[fb + r2];
        if (s + (int)(r3 >> 4) < e) v3 = feat[fb + r3];
    }

    // burst stores
    f4* o = out + (unsigned)m * (MAXA * ROWF4);
    o[base]        = v0;
    o[base + 256u] = v1;
    o[base + 512u] = v2;
    o[base + 768u] = v3;
}

extern "C" void kernel_launch(void* const* d_in, const int* in_sizes, int n_in,
                              void* d_out, int out_size, void* d_ws, size_t ws_size,
                              hipStream_t stream) {
    const float* feat = (const float*)d_in[0];
    const int*   ind  = (const int*)d_in[1];
    float*       out  = (float*)d_out;

    const int N = in_sizes[0] / DF;

    dim3 grid(MAXA * ROWF4 / 1024, BATCH);   // (10, 2048)
    pp_fused_kernel<<<grid, 256, 0, stream>>>(
        (const f4*)feat, ind, (f4*)out, N);
}

// Round 6
// 91.122 us; speedup vs baseline: 1.6450x; 1.6450x over previous
//
#include <hip/hip_runtime.h>

// PartitionPadding: out[m][p][:] = feat[starts[m]+p][:] if p < count[m] else 0.
// B=2048, MAX_ATOMS=640, D=64. Pure data movement: 256MB read + 335.5MB write.
//
// R6 = R1 geometry (best so far, 112.9us) + nontemporal stores + 32-bit math.
//  - starts kernel: 2049 threads, per-molecule binary search (~4us, latency-bound).
//  - gather: grid (40, 2048), 256 thr, one f4 load + one NT f4 store per thread.
//    Transient blocks in dispatch order = tight resident address window (R4/R5
//    showed persistent/spread geometries regress).

#define BATCH 2048
#define MAXA  640
#define DF    64
#define ROWF4 16            // float4 per row (64 floats)

typedef float f4 __attribute__((ext_vector_type(4)));

// starts[m] = lower_bound(ind, N, m) for m in [0, BATCH]; starts[BATCH] = N.
__global__ void pp_starts_kernel(const int* __restrict__ ind, int N,
                                 int* __restrict__ starts) {
    int m = blockIdx.x * blockDim.x + threadIdx.x;
    if (m > BATCH) return;
    if (m == BATCH) { starts[m] = N; return; }
    int lo = 0, hi = N;
    while (lo < hi) {
        int mid = (lo + hi) >> 1;
        if (ind[mid] < m) lo = mid + 1; else hi = mid;
    }
    starts[m] = lo;
}

// One f4 per thread. grid = (MAXA*16/256 = 40, BATCH), block = 256.
__global__ __launch_bounds__(256) void pp_gather_kernel(
        const f4* __restrict__ feat,
        const int* __restrict__ starts,
        f4* __restrict__ out) {
    const unsigned m   = blockIdx.y;
    const unsigned idx = blockIdx.x * 256u + threadIdx.x;  // 0 .. MAXA*16-1
    const unsigned p   = idx >> 4;    // row within molecule
    const int s = starts[m];
    const int e = starts[m + 1];

    f4 v = (f4){0.f, 0.f, 0.f, 0.f};
    const int src = s + (int)p;
    if (src < e) v = feat[(unsigned)src * ROWF4 + (idx & 15u)];

    __builtin_nontemporal_store(v, &out[m * (MAXA * ROWF4) + idx]);
}

extern "C" void kernel_launch(void* const* d_in, const int* in_sizes, int n_in,
                              void* d_out, int out_size, void* d_ws, size_t ws_size,
                              hipStream_t stream) {
    const float* feat = (const float*)d_in[0];
    const int*   ind  = (const int*)d_in[1];
    float*       out  = (float*)d_out;
    int*         starts = (int*)d_ws;   // BATCH+1 ints

    const int N = in_sizes[0] / DF;

    {
        dim3 grid((BATCH + 1 + 255) / 256);
        pp_starts_kernel<<<grid, 256, 0, stream>>>(ind, N, starts);
    }
    {
        dim3 grid(MAXA * ROWF4 / 256, BATCH);  // (40, 2048)
        pp_gather_kernel<<<grid, 256, 0, stream>>>(
            (const f4*)feat, starts, (f4*)out);
    }
}